// Round 3
// baseline (196.326 us; speedup 1.0000x reference)
//
#include <hip/hip_runtime.h>
#include <math.h>

// Rolling stats: W=64 window over (N=262144, F=32) fp32, stride 1, VALID.
// Out row t (t < N-63): [mean(32) | std(32) | min(32) | max(32) | sum(32)].
//
// Per-thread: column c + chunk of RCH=16 output rows.
//  Pass 1 (reverse over the first window t0..t0+63), split in two:
//    head j=63..16, partial unroll 16  -> running min/max/sum/sumsq only,
//      bounded load pipeline (~16 loads in flight, no spills);
//    tail j=15..0, full unroll         -> also records suffix min/max in
//      register arrays (unconditional writes -> clean SROA to 32 VGPRs).
//  Pass 2 (forward j=0..15): O(1) prefix min/max over incoming rows +
//    sliding sum/sumsq (outgoing element reloaded -> L1 hit).
//    window = op(suffix[j], prefix).
// Lanes 0..31 = 32 columns of one chunk -> every wave load/store is
// aligned 128B segments (output row stride 640B = 5*128B).
// Block swizzle groups contiguous chunks on the same XCD so the 63-row
// overlap between neighboring blocks hits the same L2.

#define WINW 64
#define RCH 16
#define NF 32

__global__ __launch_bounds__(256, 4) void rolling_stats_kernel(
    const float* __restrict__ x, float* __restrict__ out, int N, int T_out,
    int blocks_per_xcd) {
  // XCD swizzle: consecutive hardware blocks go to different XCDs (b % 8).
  // Remap so each XCD owns a contiguous range of chunks.
  int b = blockIdx.x;
  int xcd = b & 7;
  int idx = b >> 3;
  int vb = xcd * blocks_per_xcd + idx;  // virtual block: contiguous per XCD

  int tid = vb * blockDim.x + (int)threadIdx.x;
  int c = tid & (NF - 1);
  int chunk = tid >> 5;
  int nchunk = (T_out + RCH - 1) / RCH;
  if (chunk >= nchunk) return;
  int t0 = chunk * RCH;

  const float* p = x + (size_t)t0 * NF + c;  // loads fold j*128 into offsets

  float smin[RCH], smax[RCH];
  float ssum = 0.f, ssq = 0.f;
  float rmin = INFINITY, rmax = -INFINITY;

  // Pass 1 head: rows t0+63 .. t0+16 (no suffix storage).
#pragma unroll 16
  for (int j = WINW - 1; j >= RCH; --j) {
    float a = p[j * NF];
    rmin = fminf(rmin, a);
    rmax = fmaxf(rmax, a);
    ssum += a;
    ssq = fmaf(a, a, ssq);
  }
  // Pass 1 tail: rows t0+15 .. t0, recording suffix min/max.
#pragma unroll
  for (int j = RCH - 1; j >= 0; --j) {
    float a = p[j * NF];
    rmin = fminf(rmin, a);
    rmax = fmaxf(rmax, a);
    ssum += a;
    ssq = fmaf(a, a, ssq);
    smin[j] = rmin;
    smax[j] = rmax;
  }

  // Pass 2: forward over the chunk's outputs.
  float pmin = INFINITY, pmax = -INFINITY;
  float wsum = ssum, wsq = ssq;
  float* o = out + (size_t)t0 * (5 * NF) + c;
#pragma unroll
  for (int j = 0; j < RCH; ++j) {
    if (j > 0) {
      int rnew = t0 + (WINW - 1) + j;  // incoming row
      rnew = rnew < N ? rnew : N - 1;  // clamp (tail chunk; store guarded)
      float bnew = x[(size_t)rnew * NF + c];
      float aold = p[(j - 1) * NF];  // outgoing row (L1 hit)
      pmin = fminf(pmin, bnew);
      pmax = fmaxf(pmax, bnew);
      wsum += bnew - aold;
      wsq = fmaf(bnew, bnew, wsq);
      wsq = fmaf(-aold, aold, wsq);
    }
    if (t0 + j < T_out) {
      float wmin = fminf(smin[j], pmin);
      float wmax = fmaxf(smax[j], pmax);
      float mean = wsum * 0.015625f;                   // /64
      float var = fmaf(-mean, mean, wsq * 0.015625f);  // E[x^2]-E[x]^2
      var = fmaxf(var, 0.f);
      float sd = sqrtf(var);
      float* orow = o + (size_t)j * (5 * NF);
      // Write-once output: bypass L2 so the input stays resident.
      __builtin_nontemporal_store(mean, &orow[0 * NF]);
      __builtin_nontemporal_store(sd, &orow[1 * NF]);
      __builtin_nontemporal_store(wmin, &orow[2 * NF]);
      __builtin_nontemporal_store(wmax, &orow[3 * NF]);
      __builtin_nontemporal_store(wsum, &orow[4 * NF]);
    }
  }
}

extern "C" void kernel_launch(void* const* d_in, const int* in_sizes, int n_in,
                              void* d_out, int out_size, void* d_ws,
                              size_t ws_size, hipStream_t stream) {
  const float* x = (const float*)d_in[0];
  float* out = (float*)d_out;
  int N = in_sizes[0] / NF;    // 262144 rows
  int T_out = N - (WINW - 1);  // 262081 output rows
  int nchunk = (T_out + RCH - 1) / RCH;
  int nthreads = nchunk * NF;
  int nblocks = (nthreads + 255) / 256;
  int nblocks_pad = (nblocks + 7) & ~7;  // multiple of 8 for the swizzle
  int blocks_per_xcd = nblocks_pad >> 3;
  rolling_stats_kernel<<<nblocks_pad, 256, 0, stream>>>(x, out, N, T_out,
                                                        blocks_per_xcd);
}

// Round 4
// 185.140 us; speedup vs baseline: 1.0604x; 1.0604x over previous
//
#include <hip/hip_runtime.h>
#include <math.h>

// Rolling stats: W=64 window over (N=262144, F=32) fp32, stride 1, VALID.
// Out row t (t < N-63): [mean(32) | std(32) | min(32) | max(32) | sum(32)].
//
// Structure (R4): block-cooperative LDS staging + per-thread O(1) sliding.
//  - Block = 256 threads = 8 chunks x 32 columns, covers 128 output rows.
//  - Stage 192 input rows (24.5 KB) into LDS with 6 coalesced float4
//    loads/thread (the ONLY global reads). Kills the L2-latency-bound
//    window re-reads of R1-R3 (94 scattered dwords/thread -> 6 float4).
//  - Per thread (column c, 16 output rows): reverse suffix min/max scan
//    over the first window (register arrays), then forward prefix
//    min/max + sliding sum/sumsq, all reads from LDS.
//  - LDS banks: addr dword index = row*32 + c -> bank c; lanes 0..31
//    distinct banks, lanes 32..63 alias 2-way (free on gfx950, m136).
//  - Stores: 5 x 128B full-line segments per wave per output row.

#define WINW 64
#define RCH 16
#define NF 32
#define CHUNKS_PER_BLK 8
#define ROWS_PER_BLK (CHUNKS_PER_BLK * RCH)      // 128 output rows
#define STAGE_ROWS (ROWS_PER_BLK + WINW)         // 192 input rows staged

__global__ __launch_bounds__(256, 4) void rolling_stats_kernel(
    const float* __restrict__ x, float* __restrict__ out, int N, int T_out) {
  __shared__ float tile[STAGE_ROWS * NF];  // 24576 B

  int t0_blk = blockIdx.x * ROWS_PER_BLK;

  // --- Stage: 192 rows x 32 floats = 1536 float4, 6 per thread. ---
  const float4* xv = (const float4*)x;  // row r = 8 float4s at r*8
  float4* tv = (float4*)tile;
#pragma unroll
  for (int it = 0; it < (STAGE_ROWS * NF / 4) / 256; ++it) {
    int f = it * 256 + (int)threadIdx.x;
    int r = f >> 3;                 // local row
    int gr = t0_blk + r;
    gr = gr < N ? gr : N - 1;       // clamp (tail block; stores guarded)
    tv[f] = xv[(size_t)gr * (NF / 4) + (f & 7)];
  }
  __syncthreads();

  // --- Per-thread sliding window over LDS. ---
  int c = (int)threadIdx.x & (NF - 1);
  int lr0 = ((int)threadIdx.x >> 5) * RCH;  // local first output row
  int t0 = t0_blk + lr0;
  const float* tc = tile + c;

  float smin[RCH], smax[RCH];
  float ssum = 0.f, ssq = 0.f;
  float rmin = INFINITY, rmax = -INFINITY;

  // Pass 1: reverse scan of first window rows lr0+63 .. lr0.
#pragma unroll
  for (int j = WINW - 1; j >= RCH; --j) {
    float a = tc[(lr0 + j) * NF];
    rmin = fminf(rmin, a);
    rmax = fmaxf(rmax, a);
    ssum += a;
    ssq = fmaf(a, a, ssq);
  }
#pragma unroll
  for (int j = RCH - 1; j >= 0; --j) {
    float a = tc[(lr0 + j) * NF];
    rmin = fminf(rmin, a);
    rmax = fmaxf(rmax, a);
    ssum += a;
    ssq = fmaf(a, a, ssq);
    smin[j] = rmin;
    smax[j] = rmax;
  }

  // Pass 2: forward over the chunk's 16 outputs.
  float pmin = INFINITY, pmax = -INFINITY;
  float wsum = ssum, wsq = ssq;
  float* o = out + (size_t)t0 * (5 * NF) + c;
#pragma unroll
  for (int j = 0; j < RCH; ++j) {
    if (j > 0) {
      float bnew = tc[(lr0 + WINW - 1 + j) * NF];  // incoming (max lr 190)
      float aold = tc[(lr0 + j - 1) * NF];         // outgoing
      pmin = fminf(pmin, bnew);
      pmax = fmaxf(pmax, bnew);
      wsum += bnew - aold;
      wsq = fmaf(bnew, bnew, wsq);
      wsq = fmaf(-aold, aold, wsq);
    }
    if (t0 + j < T_out) {
      float wmin = fminf(smin[j], pmin);
      float wmax = fmaxf(smax[j], pmax);
      float mean = wsum * 0.015625f;                   // /64
      float var = fmaf(-mean, mean, wsq * 0.015625f);  // E[x^2]-E[x]^2
      var = fmaxf(var, 0.f);
      float sd = sqrtf(var);
      float* orow = o + (size_t)j * (5 * NF);
      orow[0 * NF] = mean;
      orow[1 * NF] = sd;
      orow[2 * NF] = wmin;
      orow[3 * NF] = wmax;
      orow[4 * NF] = wsum;
    }
  }
}

extern "C" void kernel_launch(void* const* d_in, const int* in_sizes, int n_in,
                              void* d_out, int out_size, void* d_ws,
                              size_t ws_size, hipStream_t stream) {
  const float* x = (const float*)d_in[0];
  float* out = (float*)d_out;
  int N = in_sizes[0] / NF;    // 262144 rows
  int T_out = N - (WINW - 1);  // 262081 output rows
  int nblocks = (T_out + ROWS_PER_BLK - 1) / ROWS_PER_BLK;  // 2048
  rolling_stats_kernel<<<nblocks, 256, 0, stream>>>(x, out, N, T_out);
}

// Round 5
// 183.859 us; speedup vs baseline: 1.0678x; 1.0070x over previous
//
#include <hip/hip_runtime.h>
#include <math.h>

// Rolling stats: W=64 window over (N=262144, F=32) fp32, stride 1, VALID.
// Out row t (t < N-63): [mean(32) | std(32) | min(32) | max(32) | sum(32)].
//
// R5 structure: LDS-staged tile (R4 win) + deeper per-thread chunks.
//  - Block = 256 threads = 8 chunks x 32 columns, covers 256 output rows
//    (RCH=32), stages 320 input rows (40.96 KB LDS, float4 coalesced).
//    Overlap re-fetch 1.25x (was 1.5x at RCH=16).
//  - Per thread (column c, 32 output rows): reverse suffix min/max scan of
//    the first window into register arrays; outgoing-row values ox[31]
//    cached in registers during the same scan (saves 31 LDS reads).
//    Forward pass: O(1) prefix min/max + sliding sum/sumsq from LDS.
//    LDS reads/thread: 64 + 31 = 95 b32 (was 94 per HALF the outputs).
//  - Banks: dword index = row*32 + c -> bank c; lanes 0..31 distinct
//    banks, 2-way alias across half-waves is free (m136). Zero conflicts.
//  - Stores: each instr = 2 aligned 128B segments (output row = 5*128B).

#define WINW 64
#define RCH 32
#define NF 32
#define CHUNKS_PER_BLK 8
#define ROWS_PER_BLK (CHUNKS_PER_BLK * RCH)  // 256 output rows
#define STAGE_ROWS (ROWS_PER_BLK + WINW)     // 320 input rows staged

__global__ __launch_bounds__(256, 3) void rolling_stats_kernel(
    const float* __restrict__ x, float* __restrict__ out, int N, int T_out) {
  __shared__ float tile[STAGE_ROWS * NF];  // 40960 B

  int t0_blk = blockIdx.x * ROWS_PER_BLK;

  // --- Stage: 320 rows x 32 floats = 2560 float4, 10 per thread. ---
  const float4* xv = (const float4*)x;  // row r = 8 float4s
  float4* tv = (float4*)tile;
#pragma unroll
  for (int it = 0; it < (STAGE_ROWS * NF / 4) / 256; ++it) {
    int f = it * 256 + (int)threadIdx.x;
    int r = f >> 3;            // local row
    int gr = t0_blk + r;
    gr = gr < N ? gr : N - 1;  // clamp (tail block; stores guarded)
    tv[f] = xv[(size_t)gr * (NF / 4) + (f & 7)];
  }
  __syncthreads();

  // --- Per-thread sliding window over LDS. ---
  int c = (int)threadIdx.x & (NF - 1);
  int lr0 = ((int)threadIdx.x >> 5) * RCH;  // local first output row
  int t0 = t0_blk + lr0;
  const float* tc = tile + c;

  float smin[RCH], smax[RCH];  // suffix min/max of first window
  float ox[RCH - 1];           // outgoing rows lr0 .. lr0+30 (reg-cached)
  float ssum = 0.f, ssq = 0.f;
  float rmin = INFINITY, rmax = -INFINITY;

  // Pass 1: reverse scan of first window rows lr0+63 .. lr0.
#pragma unroll
  for (int j = WINW - 1; j >= RCH; --j) {
    float a = tc[(lr0 + j) * NF];
    rmin = fminf(rmin, a);
    rmax = fmaxf(rmax, a);
    ssum += a;
    ssq = fmaf(a, a, ssq);
  }
#pragma unroll
  for (int j = RCH - 1; j >= 0; --j) {
    float a = tc[(lr0 + j) * NF];
    rmin = fminf(rmin, a);
    rmax = fmaxf(rmax, a);
    ssum += a;
    ssq = fmaf(a, a, ssq);
    smin[j] = rmin;
    smax[j] = rmax;
    if (j < RCH - 1) ox[j] = a;  // constant predicate after unroll
  }

  // Pass 2: forward over the chunk's 32 outputs.
  float pmin = INFINITY, pmax = -INFINITY;
  float wsum = ssum, wsq = ssq;
  float* o = out + (size_t)t0 * (5 * NF) + c;
#pragma unroll
  for (int j = 0; j < RCH; ++j) {
    if (j > 0) {
      float bnew = tc[(lr0 + WINW - 1 + j) * NF];  // incoming (max lr 318)
      float aold = ox[j - 1];                      // outgoing (registers)
      pmin = fminf(pmin, bnew);
      pmax = fmaxf(pmax, bnew);
      wsum += bnew - aold;
      wsq = fmaf(bnew, bnew, wsq);
      wsq = fmaf(-aold, aold, wsq);
    }
    if (t0 + j < T_out) {
      float wmin = fminf(smin[j], pmin);
      float wmax = fmaxf(smax[j], pmax);
      float mean = wsum * 0.015625f;                   // /64
      float var = fmaf(-mean, mean, wsq * 0.015625f);  // E[x^2]-E[x]^2
      var = fmaxf(var, 0.f);
      float sd = sqrtf(var);
      float* orow = o + (size_t)j * (5 * NF);
      orow[0 * NF] = mean;
      orow[1 * NF] = sd;
      orow[2 * NF] = wmin;
      orow[3 * NF] = wmax;
      orow[4 * NF] = wsum;
    }
  }
}

extern "C" void kernel_launch(void* const* d_in, const int* in_sizes, int n_in,
                              void* d_out, int out_size, void* d_ws,
                              size_t ws_size, hipStream_t stream) {
  const float* x = (const float*)d_in[0];
  float* out = (float*)d_out;
  int N = in_sizes[0] / NF;    // 262144 rows
  int T_out = N - (WINW - 1);  // 262081 output rows
  int nblocks = (T_out + ROWS_PER_BLK - 1) / ROWS_PER_BLK;  // 1024
  rolling_stats_kernel<<<nblocks, 256, 0, stream>>>(x, out, N, T_out);
}